// Round 1
// baseline (636.596 us; speedup 1.0000x reference)
//
#include <hip/hip_runtime.h>
#include <cstdint>

typedef __bf16 bf16;
typedef __bf16 bf16x4 __attribute__((ext_vector_type(4)));
typedef __bf16 bf16x8 __attribute__((ext_vector_type(8)));
typedef float  f32x4  __attribute__((ext_vector_type(4)));

#define AS1 __attribute__((address_space(1)))
#define AS3 __attribute__((address_space(3)))

static constexpr int BATCH = 4;
static constexpr int SEQ   = 2048;
static constexpr int EMB   = 1024;
static constexpr int NH    = 16;
static constexpr int HD    = 64;
static constexpr int M     = BATCH * SEQ;   // 8192

static __device__ __forceinline__ void gload_lds16(const void* g, void* l) {
  __builtin_amdgcn_global_load_lds((AS1 void*)g, (AS3 void*)l, 16, 0, 0);
}

static __device__ __forceinline__ f32x4 mfma16(bf16x8 a, bf16x8 b, f32x4 c) {
  return __builtin_amdgcn_mfma_f32_16x16x32_bf16(a, b, c, 0, 0, 0);
}

// ---------------- prep: fp32 -> bf16 cast (vectorized) ----------------
__global__ void cast_x_kernel(const float* __restrict__ in, bf16* __restrict__ out) {
  int i = blockIdx.x * 256 + threadIdx.x;            // one float4 per thread, exact grid
  float4 v = reinterpret_cast<const float4*>(in)[i];
  bf16x4 o;
  o[0] = (bf16)v.x; o[1] = (bf16)v.y; o[2] = (bf16)v.z; o[3] = (bf16)v.w;
  reinterpret_cast<bf16x4*>(out)[i] = o;
}

// ---------------- prep: transpose + cast  w[R][C] -> wt[C][R] ----------------
__global__ void transpose_cast_kernel(const float* __restrict__ w, bf16* __restrict__ wt,
                                      int R, int C) {
  __shared__ float t[32][33];
  int bx = blockIdx.x * 32;      // C dim
  int by = blockIdx.y * 32;      // R dim
  int tx = threadIdx.x & 31, ty = threadIdx.x >> 5;   // 32 x 8
#pragma unroll
  for (int dy = 0; dy < 32; dy += 8)
    t[ty + dy][tx] = w[(long)(by + ty + dy) * C + bx + tx];
  __syncthreads();
#pragma unroll
  for (int dy = 0; dy < 32; dy += 8)
    wt[(long)(bx + ty + dy) * R + by + tx] = (bf16)t[tx][ty + dy];
}

// ---------------- GEMM: C[M x N] = A[M x 1024] * Bt[N x 1024]^T + bias ----------------
// MODE 0: QKV epilogue -> q/k scaled+routed to [B,H,S,D], v to [B,H,D,S] (bf16)
// MODE 1: plain fp32 out + bias
template <int MODE>
__launch_bounds__(256, 2)
__global__ void gemm_kernel(const bf16* __restrict__ A, const bf16* __restrict__ Bt,
                            const float* __restrict__ bias,
                            bf16* __restrict__ qp, bf16* __restrict__ kp,
                            bf16* __restrict__ vp, float* __restrict__ outp) {
  __shared__ bf16 As[128 * 32];
  __shared__ bf16 Bs[128 * 32];
  const int tid = threadIdx.x, lane = tid & 63, wave = tid >> 6;
  const int wr = wave >> 1, wc = wave & 1;
  const int l15 = lane & 15, lg = lane >> 4;
  const int mBase = blockIdx.y * 128, nBase = blockIdx.x * 128;

  f32x4 acc[4][4] = {};

  for (int k0 = 0; k0 < 1024; k0 += 32) {
    __syncthreads();   // previous compute done before overwriting LDS
#pragma unroll
    for (int p = 0; p < 2; ++p) {
      int cbase = (p * 4 + wave) * 64;     // wave-uniform chunk base
      int c = cbase + lane;                // per-lane chunk (16B = 8 bf16)
      int row = c >> 2, kc = (c & 3) << 3;
      gload_lds16(&A[(long)(mBase + row) * 1024 + k0 + kc], &As[cbase * 8]);
      gload_lds16(&Bt[(long)(nBase + row) * 1024 + k0 + kc], &Bs[cbase * 8]);
    }
    __syncthreads();   // drains vmcnt -> LDS ready

    bf16x8 af[4], bfp[4];
#pragma unroll
    for (int m = 0; m < 4; ++m)
      af[m] = *reinterpret_cast<const bf16x8*>(&As[(wr * 64 + m * 16 + l15) * 32 + lg * 8]);
#pragma unroll
    for (int n = 0; n < 4; ++n)
      bfp[n] = *reinterpret_cast<const bf16x8*>(&Bs[(wc * 64 + n * 16 + l15) * 32 + lg * 8]);
#pragma unroll
    for (int m = 0; m < 4; ++m)
#pragma unroll
      for (int n = 0; n < 4; ++n)
        acc[m][n] = mfma16(af[m], bfp[n], acc[m][n]);
  }

  // epilogue: C/D layout col = lane&15, row = (lane>>4)*4 + reg
#pragma unroll
  for (int m = 0; m < 4; ++m) {
#pragma unroll
    for (int n = 0; n < 4; ++n) {
      int col = nBase + wc * 64 + n * 16 + l15;
      float bcol = bias[col];
#pragma unroll
      for (int r = 0; r < 4; ++r) {
        int row = mBase + wr * 64 + m * 16 + lg * 4 + r;
        float v = acc[m][n][r] + bcol;
        if constexpr (MODE == 0) {
          int b = row >> 11, s = row & 2047;
          int which = col >> 10, cc = col & 1023;
          int h = cc >> 6, d = cc & 63;
          long bh = (long)(b * NH + h);
          if (which == 0)       qp[(bh * SEQ + s) * HD + d] = (bf16)(v * 0.125f);
          else if (which == 1)  kp[(bh * SEQ + s) * HD + d] = (bf16)v;
          else                  vp[(bh * HD + d) * SEQ + s] = (bf16)v;
        } else {
          outp[(long)row * 1024 + col] = v;
        }
      }
    }
  }
}

// ---------------- flash attention: per wave 16 q-rows, 32-key tiles ----------------
__launch_bounds__(256, 2)
__global__ void attn_kernel(const bf16* __restrict__ q, const bf16* __restrict__ k,
                            const bf16* __restrict__ vT, bf16* __restrict__ att) {
  __shared__ bf16 Pl[4][16][32];
  const int tid = threadIdx.x, lane = tid & 63, wave = tid >> 6;
  const int l15 = lane & 15, lg = lane >> 4;
  const int bh = blockIdx.y;                  // 0..63
  const int b = bh >> 4, h = bh & 15;
  const int qbase = blockIdx.x * 64 + wave * 16;

  const bf16* Q  = q  + (long)bh * SEQ * HD;
  const bf16* K  = k  + (long)bh * SEQ * HD;
  const bf16* VT = vT + (long)bh * HD * SEQ;

  // Q fragments (held in registers for whole kernel); q already scaled by 1/8
  bf16x8 qf0 = *reinterpret_cast<const bf16x8*>(&Q[(qbase + l15) * HD + lg * 8]);
  bf16x8 qf1 = *reinterpret_cast<const bf16x8*>(&Q[(qbase + l15) * HD + 32 + lg * 8]);

  f32x4 o[4] = {};
  float mrow[4], lrow[4];
#pragma unroll
  for (int r = 0; r < 4; ++r) { mrow[r] = -INFINITY; lrow[r] = 0.f; }

  for (int kt = 0; kt < SEQ; kt += 32) {
    f32x4 s0 = {}, s1 = {};
    bf16x8 k0a = *reinterpret_cast<const bf16x8*>(&K[(kt + l15) * HD + lg * 8]);
    bf16x8 k0b = *reinterpret_cast<const bf16x8*>(&K[(kt + l15) * HD + 32 + lg * 8]);
    bf16x8 k1a = *reinterpret_cast<const bf16x8*>(&K[(kt + 16 + l15) * HD + lg * 8]);
    bf16x8 k1b = *reinterpret_cast<const bf16x8*>(&K[(kt + 16 + l15) * HD + 32 + lg * 8]);
    s0 = mfma16(qf0, k0a, s0);
    s0 = mfma16(qf1, k0b, s0);
    s1 = mfma16(qf0, k1a, s1);
    s1 = mfma16(qf1, k1b, s1);

    float alpha[4];
#pragma unroll
    for (int r = 0; r < 4; ++r) {
      float mx = fmaxf(s0[r], s1[r]);
      mx = fmaxf(mx, __shfl_xor(mx, 1));
      mx = fmaxf(mx, __shfl_xor(mx, 2));
      mx = fmaxf(mx, __shfl_xor(mx, 4));
      mx = fmaxf(mx, __shfl_xor(mx, 8));
      float mnew = fmaxf(mrow[r], mx);
      float p0 = __expf(s0[r] - mnew);
      float p1 = __expf(s1[r] - mnew);
      float a  = __expf(mrow[r] - mnew);   // first iter: exp(-inf)=0
      mrow[r] = mnew;
      float rs = p0 + p1;
      rs += __shfl_xor(rs, 1);
      rs += __shfl_xor(rs, 2);
      rs += __shfl_xor(rs, 4);
      rs += __shfl_xor(rs, 8);
      lrow[r] = lrow[r] * a + rs;
      alpha[r] = a;
      Pl[wave][lg * 4 + r][l15]      = (bf16)p0;
      Pl[wave][lg * 4 + r][16 + l15] = (bf16)p1;
    }
#pragma unroll
    for (int n = 0; n < 4; ++n) {
      o[n][0] *= alpha[0]; o[n][1] *= alpha[1];
      o[n][2] *= alpha[2]; o[n][3] *= alpha[3];
    }
    // P as A-operand: contiguous 8 keys per lane (per-wave private LDS, no barrier)
    bf16x8 pa = *reinterpret_cast<const bf16x8*>(&Pl[wave][l15][lg * 8]);
#pragma unroll
    for (int n = 0; n < 4; ++n) {
      bf16x8 vf = *reinterpret_cast<const bf16x8*>(&VT[(n * 16 + l15) * SEQ + kt + lg * 8]);
      o[n] = mfma16(pa, vf, o[n]);
    }
  }

  // write [B,S,H*D] bf16
#pragma unroll
  for (int n = 0; n < 4; ++n) {
#pragma unroll
    for (int r = 0; r < 4; ++r) {
      int row = qbase + lg * 4 + r;
      att[((long)(b * SEQ + row)) * EMB + h * HD + n * 16 + l15] = (bf16)(o[n][r] / lrow[r]);
    }
  }
}

extern "C" void kernel_launch(void* const* d_in, const int* in_sizes, int n_in,
                              void* d_out, int out_size, void* d_ws, size_t ws_size,
                              hipStream_t stream) {
  (void)in_sizes; (void)n_in; (void)out_size; (void)ws_size;
  const float* x     = (const float*)d_in[0];
  const float* w_qkv = (const float*)d_in[1];
  const float* b_qkv = (const float*)d_in[2];
  const float* w_fc  = (const float*)d_in[3];
  const float* b_fc  = (const float*)d_in[4];
  float* out = (float*)d_out;

  uint8_t* ws = (uint8_t*)d_ws;
  const size_t MB = 1024u * 1024u;
  bf16* xb    = (bf16*)(ws + 0 * MB);    // 16 MB  [M][1024]    (reused as att after GEMM1)
  bf16* wqkvT = (bf16*)(ws + 16 * MB);   //  6 MB  [3072][1024]
  bf16* wfcT  = (bf16*)(ws + 22 * MB);   //  2 MB  [1024][1024]
  bf16* qp    = (bf16*)(ws + 24 * MB);   // 16 MB  [B,H,S,D]  (pre-scaled 1/8)
  bf16* kp    = (bf16*)(ws + 40 * MB);   // 16 MB  [B,H,S,D]
  bf16* vp    = (bf16*)(ws + 56 * MB);   // 16 MB  [B,H,D,S]
  bf16* att   = xb;                      // alias: xb dead after GEMM1

  cast_x_kernel<<<(M * EMB) / 4 / 256, 256, 0, stream>>>(x, xb);
  transpose_cast_kernel<<<dim3(3 * EMB / 32, EMB / 32), 256, 0, stream>>>(w_qkv, wqkvT, EMB, 3 * EMB);
  transpose_cast_kernel<<<dim3(EMB / 32, EMB / 32), 256, 0, stream>>>(w_fc, wfcT, EMB, EMB);

  gemm_kernel<0><<<dim3(3 * EMB / 128, M / 128), 256, 0, stream>>>(
      xb, wqkvT, b_qkv, qp, kp, vp, nullptr);

  attn_kernel<<<dim3(SEQ / 64, BATCH * NH), 256, 0, stream>>>(qp, kp, vp, att);

  gemm_kernel<1><<<dim3(EMB / 128, M / 128), 256, 0, stream>>>(
      att, wfcT, b_fc, nullptr, nullptr, nullptr, out);
}

// Round 2
// 362.359 us; speedup vs baseline: 1.7568x; 1.7568x over previous
//
#include <hip/hip_runtime.h>
#include <cstdint>

typedef __bf16 bf16;
typedef __bf16 bf16x2 __attribute__((ext_vector_type(2)));
typedef __bf16 bf16x4 __attribute__((ext_vector_type(4)));
typedef __bf16 bf16x8 __attribute__((ext_vector_type(8)));
typedef float  f32x4  __attribute__((ext_vector_type(4)));

#define AS1 __attribute__((address_space(1)))
#define AS3 __attribute__((address_space(3)))

static constexpr int BATCH = 4;
static constexpr int SEQ   = 2048;
static constexpr int EMB   = 1024;
static constexpr int NH    = 16;
static constexpr int HD    = 64;
static constexpr int M     = BATCH * SEQ;   // 8192

static __device__ __forceinline__ void gload_lds16(const void* g, void* l) {
  __builtin_amdgcn_global_load_lds((AS1 void*)g, (AS3 void*)l, 16, 0, 0);
}

static __device__ __forceinline__ f32x4 mfma16(bf16x8 a, bf16x8 b, f32x4 c) {
  return __builtin_amdgcn_mfma_f32_16x16x32_bf16(a, b, c, 0, 0, 0);
}

// ---------------- prep: fp32 -> bf16 cast (vectorized) ----------------
__global__ void cast_x_kernel(const float* __restrict__ in, bf16* __restrict__ out) {
  int i = blockIdx.x * 256 + threadIdx.x;            // one float4 per thread, exact grid
  float4 v = reinterpret_cast<const float4*>(in)[i];
  bf16x4 o;
  o[0] = (bf16)v.x; o[1] = (bf16)v.y; o[2] = (bf16)v.z; o[3] = (bf16)v.w;
  reinterpret_cast<bf16x4*>(out)[i] = o;
}

// ---------------- prep: transpose + cast  w[R][C] -> wt[C][R] ----------------
__global__ void transpose_cast_kernel(const float* __restrict__ w, bf16* __restrict__ wt,
                                      int R, int C) {
  __shared__ float t[32][33];
  int bx = blockIdx.x * 32;      // C dim
  int by = blockIdx.y * 32;      // R dim
  int tx = threadIdx.x & 31, ty = threadIdx.x >> 5;   // 32 x 8
#pragma unroll
  for (int dy = 0; dy < 32; dy += 8)
    t[ty + dy][tx] = w[(long)(by + ty + dy) * C + bx + tx];
  __syncthreads();
#pragma unroll
  for (int dy = 0; dy < 32; dy += 8)
    wt[(long)(bx + ty + dy) * R + by + tx] = (bf16)t[tx][ty + dy];
}

// ---------------- GEMM: C[M x N] = A[M x 1024] * Bt[N x 1024]^T + bias ----------------
// MODE 0: QKV epilogue -> q/k scaled+routed to [B,H,S,D], v to [B,H,D,S] (bf16)
// MODE 1: plain fp32 out + bias
template <int MODE>
__launch_bounds__(256, 2)
__global__ void gemm_kernel(const bf16* __restrict__ A, const bf16* __restrict__ Bt,
                            const float* __restrict__ bias,
                            bf16* __restrict__ qp, bf16* __restrict__ kp,
                            bf16* __restrict__ vp, float* __restrict__ outp) {
  __shared__ bf16 As[128 * 32];
  __shared__ bf16 Bs[128 * 32];
  const int tid = threadIdx.x, lane = tid & 63, wave = tid >> 6;
  const int wr = wave >> 1, wc = wave & 1;
  const int l15 = lane & 15, lg = lane >> 4;
  const int mBase = blockIdx.y * 128, nBase = blockIdx.x * 128;

  f32x4 acc[4][4] = {};

  for (int k0 = 0; k0 < 1024; k0 += 32) {
    __syncthreads();   // previous compute done before overwriting LDS
#pragma unroll
    for (int p = 0; p < 2; ++p) {
      int cbase = (p * 4 + wave) * 64;     // wave-uniform chunk base
      int c = cbase + lane;                // per-lane chunk (16B = 8 bf16)
      int row = c >> 2, kc = (c & 3) << 3;
      gload_lds16(&A[(long)(mBase + row) * 1024 + k0 + kc], &As[cbase * 8]);
      gload_lds16(&Bt[(long)(nBase + row) * 1024 + k0 + kc], &Bs[cbase * 8]);
    }
    __syncthreads();   // drains vmcnt -> LDS ready

    bf16x8 af[4], bfp[4];
#pragma unroll
    for (int m = 0; m < 4; ++m)
      af[m] = *reinterpret_cast<const bf16x8*>(&As[(wr * 64 + m * 16 + l15) * 32 + lg * 8]);
#pragma unroll
    for (int n = 0; n < 4; ++n)
      bfp[n] = *reinterpret_cast<const bf16x8*>(&Bs[(wc * 64 + n * 16 + l15) * 32 + lg * 8]);
#pragma unroll
    for (int m = 0; m < 4; ++m)
#pragma unroll
      for (int n = 0; n < 4; ++n)
        acc[m][n] = mfma16(af[m], bfp[n], acc[m][n]);
  }

  // epilogue: C/D layout col = lane&15, row = (lane>>4)*4 + reg
#pragma unroll
  for (int m = 0; m < 4; ++m) {
#pragma unroll
    for (int n = 0; n < 4; ++n) {
      int col = nBase + wc * 64 + n * 16 + l15;
      float bcol = bias[col];
#pragma unroll
      for (int r = 0; r < 4; ++r) {
        int row = mBase + wr * 64 + m * 16 + lg * 4 + r;
        float v = acc[m][n][r] + bcol;
        if constexpr (MODE == 0) {
          int b = row >> 11, s = row & 2047;
          int which = col >> 10, cc = col & 1023;
          int h = cc >> 6, d = cc & 63;
          long bh = (long)(b * NH + h);
          if (which == 0)       qp[(bh * SEQ + s) * HD + d] = (bf16)(v * 0.125f);
          else if (which == 1)  kp[(bh * SEQ + s) * HD + d] = (bf16)v;
          else                  vp[(bh * HD + d) * SEQ + s] = (bf16)v;
        } else {
          outp[(long)row * 1024 + col] = v;
        }
      }
    }
  }
}

// ---------------- flash attention v2: swapped QK^T / swapped PV ----------------
// Per wave: 32 q-rows. Per 32-key tile:
//   S^T = mfma(K, Q)  -> lane holds 8 scores for ONE q-row (q = lane&15 within group)
//   softmax: in-register max/sum over 8 + 2 shfl_xor (16,32)   [all 16 rows parallel]
//   P^T redistributed k-wise via tiny wave-private LDS (80B pitch, 16B-aligned rows)
//   O^T += mfma(V^T, P^T) -> alpha rescale is per-lane (q = lane&15), no redistribution
__launch_bounds__(256, 2)
__global__ void attn_kernel(const bf16* __restrict__ q, const bf16* __restrict__ k,
                            const bf16* __restrict__ vT, bf16* __restrict__ att) {
  __shared__ __align__(16) bf16 Pl[4][32][40];   // 80B pitch per row
  const int tid = threadIdx.x, lane = tid & 63, wave = tid >> 6;
  const int l15 = lane & 15, lg = lane >> 4;
  const int bh = blockIdx.y;                  // 0..63
  const int b = bh >> 4, h = bh & 15;
  const int qbase = blockIdx.x * 128 + wave * 32;

  const bf16* Q  = q  + (long)bh * SEQ * HD;
  const bf16* K  = k  + (long)bh * SEQ * HD;
  const bf16* VT = vT + (long)bh * HD * SEQ;

  // Q fragments: [qgroup g][d-half]; q already pre-scaled by 1/8
  bf16x8 qf[2][2];
#pragma unroll
  for (int g = 0; g < 2; ++g) {
    qf[g][0] = *reinterpret_cast<const bf16x8*>(&Q[(qbase + g * 16 + l15) * HD + lg * 8]);
    qf[g][1] = *reinterpret_cast<const bf16x8*>(&Q[(qbase + g * 16 + l15) * HD + 32 + lg * 8]);
  }

  f32x4 o[2][4] = {};          // O^T accum: [qgroup][d-block]; col=l15=q, row=lg*4+r=d
  float mrow[2] = {-INFINITY, -INFINITY};
  float lrow[2] = {0.f, 0.f};

  for (int kt = 0; kt < SEQ; kt += 32) {
    // K fragments: [kgroup j][d-half]
    bf16x8 ka[2][2];
#pragma unroll
    for (int j = 0; j < 2; ++j) {
      ka[j][0] = *reinterpret_cast<const bf16x8*>(&K[(kt + j * 16 + l15) * HD + lg * 8]);
      ka[j][1] = *reinterpret_cast<const bf16x8*>(&K[(kt + j * 16 + l15) * HD + 32 + lg * 8]);
    }
    // V^T fragments (issue early; consumed after softmax)
    bf16x8 vf[4];
#pragma unroll
    for (int n = 0; n < 4; ++n)
      vf[n] = *reinterpret_cast<const bf16x8*>(&VT[(n * 16 + l15) * SEQ + kt + lg * 8]);

    // S^T[k][q]: s[g][j][r] = score(q = g-group lane&15, k = j*16 + lg*4 + r)
    f32x4 s[2][2] = {};
#pragma unroll
    for (int g = 0; g < 2; ++g)
#pragma unroll
      for (int j = 0; j < 2; ++j) {
        s[g][j] = mfma16(ka[j][0], qf[g][0], s[g][j]);
        s[g][j] = mfma16(ka[j][1], qf[g][1], s[g][j]);
      }

    float alpha[2];
#pragma unroll
    for (int g = 0; g < 2; ++g) {
      float mx = fmaxf(fmaxf(fmaxf(s[g][0][0], s[g][0][1]), fmaxf(s[g][0][2], s[g][0][3])),
                       fmaxf(fmaxf(s[g][1][0], s[g][1][1]), fmaxf(s[g][1][2], s[g][1][3])));
      mx = fmaxf(mx, __shfl_xor(mx, 16));
      mx = fmaxf(mx, __shfl_xor(mx, 32));
      float mnew = fmaxf(mrow[g], mx);
      float p0[4], p1[4];
#pragma unroll
      for (int r = 0; r < 4; ++r) {
        p0[r] = __expf(s[g][0][r] - mnew);
        p1[r] = __expf(s[g][1][r] - mnew);
      }
      float al = __expf(mrow[g] - mnew);      // first iter: exp(-inf) = 0
      mrow[g] = mnew;
      float rs = (p0[0] + p0[1]) + (p0[2] + p0[3]) + (p1[0] + p1[1]) + (p1[2] + p1[3]);
      rs += __shfl_xor(rs, 16);
      rs += __shfl_xor(rs, 32);
      lrow[g] = lrow[g] * al + rs;
      alpha[g] = al;
      // pack & stage P^T slice: row = q_local, cols k = lg*4..+3 and 16+lg*4..+3
      bf16x4 w0, w1;
#pragma unroll
      for (int r = 0; r < 4; ++r) { w0[r] = (bf16)p0[r]; w1[r] = (bf16)p1[r]; }
      *reinterpret_cast<bf16x4*>(&Pl[wave][g * 16 + l15][lg * 4])      = w0;
      *reinterpret_cast<bf16x4*>(&Pl[wave][g * 16 + l15][16 + lg * 4]) = w1;
    }

    // rescale O^T history (alpha indexed by q = lane&15 -> per-lane scalar)
#pragma unroll
    for (int g = 0; g < 2; ++g)
#pragma unroll
      for (int n = 0; n < 4; ++n) {
        o[g][n][0] *= alpha[g]; o[g][n][1] *= alpha[g];
        o[g][n][2] *= alpha[g]; o[g][n][3] *= alpha[g];
      }

    // P^T as B-operand: lane reads k = lg*8..+7 of its q-row (wave-private, no barrier)
    bf16x8 pb[2];
#pragma unroll
    for (int g = 0; g < 2; ++g)
      pb[g] = *reinterpret_cast<const bf16x8*>(&Pl[wave][g * 16 + l15][lg * 8]);
#pragma unroll
    for (int g = 0; g < 2; ++g)
#pragma unroll
      for (int n = 0; n < 4; ++n)
        o[g][n] = mfma16(vf[n], pb[g], o[g][n]);
  }

  // epilogue: lane holds O^T for q = qbase + g*16 + l15, d = n*16 + lg*4 + r
#pragma unroll
  for (int g = 0; g < 2; ++g) {
    float inv = 1.f / lrow[g];
    long rowoff = ((long)(b * SEQ + qbase + g * 16 + l15)) * EMB + h * HD;
#pragma unroll
    for (int n = 0; n < 4; ++n)
#pragma unroll
      for (int r = 0; r < 4; r += 2) {
        bf16x2 pr;
        pr[0] = (bf16)(o[g][n][r] * inv);
        pr[1] = (bf16)(o[g][n][r + 1] * inv);
        *reinterpret_cast<bf16x2*>(&att[rowoff + n * 16 + lg * 4 + r]) = pr;
      }
  }
}

extern "C" void kernel_launch(void* const* d_in, const int* in_sizes, int n_in,
                              void* d_out, int out_size, void* d_ws, size_t ws_size,
                              hipStream_t stream) {
  (void)in_sizes; (void)n_in; (void)out_size; (void)ws_size;
  const float* x     = (const float*)d_in[0];
  const float* w_qkv = (const float*)d_in[1];
  const float* b_qkv = (const float*)d_in[2];
  const float* w_fc  = (const float*)d_in[3];
  const float* b_fc  = (const float*)d_in[4];
  float* out = (float*)d_out;

  uint8_t* ws = (uint8_t*)d_ws;
  const size_t MB = 1024u * 1024u;
  bf16* xb    = (bf16*)(ws + 0 * MB);    // 16 MB  [M][1024]    (reused as att after GEMM1)
  bf16* wqkvT = (bf16*)(ws + 16 * MB);   //  6 MB  [3072][1024]
  bf16* wfcT  = (bf16*)(ws + 22 * MB);   //  2 MB  [1024][1024]
  bf16* qp    = (bf16*)(ws + 24 * MB);   // 16 MB  [B,H,S,D]  (pre-scaled 1/8)
  bf16* kp    = (bf16*)(ws + 40 * MB);   // 16 MB  [B,H,S,D]
  bf16* vp    = (bf16*)(ws + 56 * MB);   // 16 MB  [B,H,D,S]
  bf16* att   = xb;                      // alias: xb dead after GEMM1

  cast_x_kernel<<<(M * EMB) / 4 / 256, 256, 0, stream>>>(x, xb);
  transpose_cast_kernel<<<dim3(3 * EMB / 32, EMB / 32), 256, 0, stream>>>(w_qkv, wqkvT, EMB, 3 * EMB);
  transpose_cast_kernel<<<dim3(EMB / 32, EMB / 32), 256, 0, stream>>>(w_fc, wfcT, EMB, EMB);

  gemm_kernel<0><<<dim3(3 * EMB / 128, M / 128), 256, 0, stream>>>(
      xb, wqkvT, b_qkv, qp, kp, vp, nullptr);

  attn_kernel<<<dim3(SEQ / 128, BATCH * NH), 256, 0, stream>>>(qp, kp, vp, att);

  gemm_kernel<1><<<dim3(EMB / 128, M / 128), 256, 0, stream>>>(
      att, wfcT, b_fc, nullptr, nullptr, nullptr, out);
}